// Round 1
// baseline (2338.269 us; speedup 1.0000x reference)
//
#include <hip/hip_runtime.h>
#include <hip/hip_bf16.h>
#include <math.h>

typedef unsigned short u16;
typedef short bf16x8 __attribute__((ext_vector_type(8)));
typedef float f32x4 __attribute__((ext_vector_type(4)));

#define B_ 2
#define T_ 2048
#define E_ 1024
#define HQ_ 16
#define HKV_ 4
#define D_ 64
#define G_ 4

__device__ __forceinline__ u16 f2bf(float f) {
    union { float f; unsigned int i; } v; v.f = f;
    unsigned int x = v.i;
    return (u16)((x + 0x7fffu + ((x >> 16) & 1u)) >> 16);
}

__device__ __forceinline__ bf16x8 cvt8(const float* p) {
    float4 a = *(const float4*)p;
    float4 b = *(const float4*)(p + 4);
    bf16x8 r;
    r[0] = (short)f2bf(a.x); r[1] = (short)f2bf(a.y);
    r[2] = (short)f2bf(a.z); r[3] = (short)f2bf(a.w);
    r[4] = (short)f2bf(b.x); r[5] = (short)f2bf(b.y);
    r[6] = (short)f2bf(b.z); r[7] = (short)f2bf(b.w);
    return r;
}

// ---------------- fp32 -> bf16 bulk converter (RNE, identical rounding to the old in-loop f2bf)
__global__ __launch_bounds__(256) void convert_bf16(const float* __restrict__ src,
                                                    u16* __restrict__ dst, int n8) {
    int i = blockIdx.x * blockDim.x + threadIdx.x;
    if (i >= n8) return;
    bf16x8 r = cvt8(src + (size_t)i * 8);
    *(bf16x8*)(dst + (size_t)i * 8) = r;
}

// ---------------- RoPE cos/sin table: 2048 x 32 unique (t, ii) pairs, double precision
// (exactly the math the old per-element kernel did 40x redundantly)
__global__ __launch_bounds__(256) void rope_table(float* __restrict__ ct, float* __restrict__ st) {
    int gid = blockIdx.x * blockDim.x + threadIdx.x;   // 65536
    int t = gid >> 5, ii = gid & 31;
    double theta = pow(10000.0, -(double)ii / 32.0);
    double ang = (double)(t + 1) * theta;
    ct[gid] = (float)cos(ang);
    st[gid] = (float)sin(ang);
}

// ---------------- QKV projection: C(4096x1536) = X(4096x1024) @ [Wq|Wk|Wv] + bias
// bf16 pre-converted inputs; fp32 accumulate/out.
__global__ __launch_bounds__(256) void qkv_gemm(
    const u16* __restrict__ Xb,
    const u16* __restrict__ Wqb, const u16* __restrict__ Wkb, const u16* __restrict__ Wvb,
    const float* __restrict__ bq, const float* __restrict__ bk, const float* __restrict__ bv,
    float* __restrict__ qws, float* __restrict__ kws, float* __restrict__ vws)
{
    int lane = threadIdx.x & 63;
    int wave = threadIdx.x >> 6;
    int l16 = lane & 15;
    int quad = lane >> 4;
    int mtile = blockIdx.y;                 // 0..255
    int ntile = blockIdx.x * 4 + wave;      // 0..95
    int m = mtile * 16 + l16;
    int n = ntile * 16 + l16;

    const u16* W; int ldw; const float* bias; int ncol;
    if (n < 1024)      { W = Wqb; ldw = 1024; bias = bq; ncol = n; }
    else if (n < 1280) { W = Wkb; ldw = 256;  bias = bk; ncol = n - 1024; }
    else               { W = Wvb; ldw = 256;  bias = bv; ncol = n - 1280; }

    f32x4 acc = {0.f, 0.f, 0.f, 0.f};
    const u16* arow = Xb + (size_t)m * 1024 + quad * 8;
    for (int kk = 0; kk < 1024; kk += 32) {
        bf16x8 a = *(const bf16x8*)(arow + kk);           // one 16B load
        const u16* wp = W + (size_t)(kk + quad * 8) * ldw + ncol;
        bf16x8 b;
        #pragma unroll
        for (int j = 0; j < 8; ++j) b[j] = (short)wp[(size_t)j * ldw];
        acc = __builtin_amdgcn_mfma_f32_16x16x32_bf16(a, b, acc, 0, 0, 0);
    }

    float bs = bias[ncol];
    #pragma unroll
    for (int r = 0; r < 4; ++r) {
        int rowm = mtile * 16 + quad * 4 + r;
        int bb = rowm >> 11, t = rowm & (T_ - 1);
        float h = acc[r] + bs;
        if (n < 1024) {
            int hq = n >> 6, dd = n & 63;
            qws[(((size_t)(bb * HQ_ + hq)) * T_ + t) * D_ + dd] = h;
        } else if (n < 1280) {
            int c2 = n - 1024; int kvh = c2 >> 6, dd = c2 & 63;
            kws[(((size_t)(bb * HKV_ + kvh)) * T_ + t) * D_ + dd] = h;
        } else {
            int c2 = n - 1280; int kvh = c2 >> 6, dd = c2 & 63;
            vws[(((size_t)(bb * HKV_ + kvh)) * T_ + t) * D_ + dd] = h;
        }
    }
}

// ---------------- RoPE apply in place (fp32), table-driven
__global__ void rope_apply(float* __restrict__ qws, float* __restrict__ kws,
                           const float* __restrict__ ct, const float* __restrict__ st) {
    const int QP = B_ * HQ_ * T_ * 32;   // 2,097,152
    const int KP = B_ * HKV_ * T_ * 32;  //   524,288
    int gid = blockIdx.x * blockDim.x + threadIdx.x;
    if (gid >= QP + KP) return;
    float* base; int row;
    if (gid < QP) { row = gid >> 5; base = qws + (size_t)row * 64; }
    else          { row = (gid - QP) >> 5; base = kws + (size_t)row * 64; }
    int ii = gid & 31;
    int t = row & (T_ - 1);
    float c = ct[t * 32 + ii];
    float s = st[t * 32 + ii];
    float x1 = base[ii];
    float x2 = base[ii + 32];
    base[ii]      = x1 * c - x2 * s;
    base[ii + 32] = x2 * c + x1 * s;
}

// ---------------- attention: one block per (b,hq, 4 query rows). fp32 throughout. (unchanged)
__global__ __launch_bounds__(256) void attn_kernel(
    float* __restrict__ qws, const float* __restrict__ kws, const float* __restrict__ vws,
    float* __restrict__ att_out)
{
    __shared__ __align__(16) float s2[T_ * 4];     // 32 KB
    __shared__ __align__(16) float q_s[4 * 64];    // [r*64 + c]
    __shared__ __align__(16) float red[1024];
    __shared__ float s_inv[4];
    int tid = threadIdx.x;
    int lane = tid & 63, wave = tid >> 6;
    int i0 = blockIdx.x * 4;
    int imax = i0 + 3;
    int bh = blockIdx.y;
    int b = bh >> 4, hq = bh & 15;
    int kvh = hq >> 2, g = hq & 3;
    float* qbase = qws + ((size_t)bh * T_ + i0) * 64;
    const float* kb = kws + ((size_t)(b * HKV_ + kvh) * T_) * 64;
    const float* vb = vws + ((size_t)(b * HKV_ + kvh) * T_) * 64;
    q_s[tid] = qbase[tid];          // 4 rows x 64 = 256
    __syncthreads();

    // ---- scores: register-tiled 4 j's x 4 rows per thread per pass
    for (int jb = tid; jb <= imax; jb += 1024) {
        int js1 = jb + 256, js2 = jb + 512, js3 = jb + 768;
        const float4* kp0 = (const float4*)(kb + (size_t)jb * 64);
        const float4* kp1 = (const float4*)(kb + (size_t)(js1 <= imax ? js1 : imax) * 64);
        const float4* kp2 = (const float4*)(kb + (size_t)(js2 <= imax ? js2 : imax) * 64);
        const float4* kp3 = (const float4*)(kb + (size_t)(js3 <= imax ? js3 : imax) * 64);
        const float4* kp[4] = {kp0, kp1, kp2, kp3};
        float acc[4][4] = {};
        #pragma unroll
        for (int c = 0; c < 16; ++c) {
            float4 qv[4];
            #pragma unroll
            for (int r = 0; r < 4; ++r) qv[r] = *(const float4*)(q_s + r * 64 + c * 4);
            #pragma unroll
            for (int jj = 0; jj < 4; ++jj) {
                float4 u = kp[jj][c];
                #pragma unroll
                for (int r = 0; r < 4; ++r)
                    acc[jj][r] += qv[r].x * u.x + qv[r].y * u.y + qv[r].z * u.z + qv[r].w * u.w;
            }
        }
        int js[4] = {jb, js1, js2, js3};
        #pragma unroll
        for (int jj = 0; jj < 4; ++jj) {
            if (js[jj] <= imax) {
                float4 sv;
                sv.x = acc[jj][0] * 0.125f; sv.y = acc[jj][1] * 0.125f;
                sv.z = acc[jj][2] * 0.125f; sv.w = acc[jj][3] * 0.125f;
                *(float4*)(s2 + (size_t)js[jj] * 4) = sv;
            }
        }
    }
    __syncthreads();

    // ---- row max (causal-aware)
    float mr[4] = {-1e30f, -1e30f, -1e30f, -1e30f};
    for (int j = tid; j <= imax; j += 256) {
        float4 sv = *(const float4*)(s2 + (size_t)j * 4);
        if (j <= i0)     mr[0] = fmaxf(mr[0], sv.x);
        if (j <= i0 + 1) mr[1] = fmaxf(mr[1], sv.y);
        if (j <= i0 + 2) mr[2] = fmaxf(mr[2], sv.z);
        mr[3] = fmaxf(mr[3], sv.w);
    }
    #pragma unroll
    for (int off = 32; off; off >>= 1) {
        #pragma unroll
        for (int r = 0; r < 4; ++r) mr[r] = fmaxf(mr[r], __shfl_down(mr[r], off, 64));
    }
    if (lane == 0) {
        #pragma unroll
        for (int r = 0; r < 4; ++r) red[wave * 4 + r] = mr[r];
    }
    __syncthreads();
    #pragma unroll
    for (int r = 0; r < 4; ++r)
        mr[r] = fmaxf(fmaxf(red[r], red[4 + r]), fmaxf(red[8 + r], red[12 + r]));
    __syncthreads();   // protect red before reuse

    // ---- exp + sum (masked entries -> 0)
    float sr[4] = {0.f, 0.f, 0.f, 0.f};
    for (int j = tid; j <= imax; j += 256) {
        float4 sv = *(const float4*)(s2 + (size_t)j * 4);
        float p0 = (j <= i0)     ? __expf(sv.x - mr[0]) : 0.f;
        float p1 = (j <= i0 + 1) ? __expf(sv.y - mr[1]) : 0.f;
        float p2 = (j <= i0 + 2) ? __expf(sv.z - mr[2]) : 0.f;
        float p3 =                 __expf(sv.w - mr[3]);
        sr[0] += p0; sr[1] += p1; sr[2] += p2; sr[3] += p3;
        float4 pv; pv.x = p0; pv.y = p1; pv.z = p2; pv.w = p3;
        *(float4*)(s2 + (size_t)j * 4) = pv;
    }
    #pragma unroll
    for (int off = 32; off; off >>= 1) {
        #pragma unroll
        for (int r = 0; r < 4; ++r) sr[r] += __shfl_down(sr[r], off, 64);
    }
    if (lane == 0) {
        #pragma unroll
        for (int r = 0; r < 4; ++r) red[wave * 4 + r] = sr[r];
    }
    __syncthreads();
    float inv[4];
    #pragma unroll
    for (int r = 0; r < 4; ++r)
        inv[r] = 1.0f / (red[r] + red[4 + r] + red[8 + r] + red[12 + r]);
    if (tid < 4) s_inv[tid] = inv[tid];
    __syncthreads();   // protect red before PV reuse; publish s_inv

    // ---- write att_weights rows (fp32), zeros beyond causal frontier
    size_t abase = (((size_t)(b * G_ + g) * HKV_ + kvh) * T_ + i0) * T_;
    for (int j = tid; j < T_; j += 256) {
        float4 pv;
        if (j <= imax) pv = *(const float4*)(s2 + (size_t)j * 4);
        else { pv.x = 0.f; pv.y = 0.f; pv.z = 0.f; pv.w = 0.f; }
        att_out[abase + 0 * T_ + j] = pv.x * inv[0];
        att_out[abase + 1 * T_ + j] = pv.y * inv[1];
        att_out[abase + 2 * T_ + j] = pv.z * inv[2];
        att_out[abase + 3 * T_ + j] = pv.w * inv[3];
    }

    // ---- P @ V : 16 j-chunks x 16 d-groups (4 dims each)
    int dg = (tid & 15) * 4;
    int chunk = tid >> 4;          // 0..15
    float acc[4][4] = {};          // [row][dd]
    for (int j = chunk; j <= imax; j += 16) {
        float4 pv = *(const float4*)(s2 + (size_t)j * 4);
        float4 vv = *(const float4*)(vb + (size_t)j * 64 + dg);
        acc[0][0] += pv.x * vv.x; acc[0][1] += pv.x * vv.y; acc[0][2] += pv.x * vv.z; acc[0][3] += pv.x * vv.w;
        acc[1][0] += pv.y * vv.x; acc[1][1] += pv.y * vv.y; acc[1][2] += pv.y * vv.z; acc[1][3] += pv.y * vv.w;
        acc[2][0] += pv.z * vv.x; acc[2][1] += pv.z * vv.y; acc[2][2] += pv.z * vv.z; acc[2][3] += pv.z * vv.w;
        acc[3][0] += pv.w * vv.x; acc[3][1] += pv.w * vv.y; acc[3][2] += pv.w * vv.z; acc[3][3] += pv.w * vv.w;
    }
    // reduce the wave's 4 chunks (lane>>4): offsets 32, 16
    #pragma unroll
    for (int off = 32; off >= 16; off >>= 1) {
        #pragma unroll
        for (int r = 0; r < 4; ++r)
            #pragma unroll
            for (int dd = 0; dd < 4; ++dd)
                acc[r][dd] += __shfl_down(acc[r][dd], off, 64);
    }
    if (lane < 16) {
        #pragma unroll
        for (int r = 0; r < 4; ++r)
            #pragma unroll
            for (int dd = 0; dd < 4; ++dd)
                red[wave * 256 + lane * 16 + r * 4 + dd] = acc[r][dd];
    }
    __syncthreads();
    // final combine across 4 waves; write y in place over this block's q rows
    {
        int r = tid >> 6, d = tid & 63;
        int dgi = d >> 2, dd = d & 3;
        int idx = dgi * 16 + r * 4 + dd;
        float y = red[idx] + red[256 + idx] + red[512 + idx] + red[768 + idx];
        qbase[r * 64 + d] = y * s_inv[r];
    }
}

// ---------------- output projection: out(4096x1024) = Y @ Wo + bo  (bf16 pre-converted inputs)
__global__ __launch_bounds__(256) void out_gemm(
    const u16* __restrict__ Yb, const u16* __restrict__ Wob, const float* __restrict__ bo,
    float* __restrict__ out)
{
    int lane = threadIdx.x & 63;
    int wave = threadIdx.x >> 6;
    int l16 = lane & 15;
    int quad = lane >> 4;
    int mtile = blockIdx.y;                 // 0..255
    int ntile = blockIdx.x * 4 + wave;      // 0..63
    int m = mtile * 16 + l16;
    int n = ntile * 16 + l16;
    int bb = m >> 11, t = m & (T_ - 1);

    f32x4 acc = {0.f, 0.f, 0.f, 0.f};
    for (int kk = 0; kk < 1024; kk += 32) {
        int ch = kk + quad * 8;            // 8-aligned, never straddles a 64-wide head
        int hq = ch >> 6, d0 = ch & 63;
        const u16* ap = Yb + (((size_t)(bb * HQ_ + hq) * T_ + t) * D_) + d0;
        bf16x8 a = *(const bf16x8*)ap;     // one 16B load
        const u16* wp = Wob + (size_t)ch * 1024 + n;
        bf16x8 b;
        #pragma unroll
        for (int j = 0; j < 8; ++j) b[j] = (short)wp[(size_t)j * 1024];
        acc = __builtin_amdgcn_mfma_f32_16x16x32_bf16(a, b, acc, 0, 0, 0);
    }
    float bs = bo[n];
    #pragma unroll
    for (int r = 0; r < 4; ++r) {
        int rowm = mtile * 16 + quad * 4 + r;
        out[(size_t)rowm * 1024 + n] = acc[r] + bs;
    }
}

extern "C" void kernel_launch(void* const* d_in, const int* in_sizes, int n_in,
                              void* d_out, int out_size, void* d_ws, size_t ws_size,
                              hipStream_t stream) {
    const float* x  = (const float*)d_in[0];
    // d_in[1] = mask (int32) — causal triu, applied analytically
    const float* Wq = (const float*)d_in[2];
    const float* bq = (const float*)d_in[3];
    const float* Wk = (const float*)d_in[4];
    const float* bk = (const float*)d_in[5];
    const float* Wv = (const float*)d_in[6];
    const float* bv = (const float*)d_in[7];
    const float* Wo = (const float*)d_in[8];
    const float* bo = (const float*)d_in[9];

    float* out = (float*)d_out;
    float* qws = (float*)d_ws;          // (B,HQ,T,D)  4,194,304 floats; later holds y fp32
    float* kws = qws + 4194304;         // (B,HKV,T,D) 1,048,576
    float* vws = kws + 1048576;         // (B,HKV,T,D) 1,048,576   -> ws total 24 MB (unchanged)
    float* att_out = out + 4194304;     // (B,G,HKV,T,T) fp32 — 537 MB, dead until attn_kernel

    // --- scratch carved from the att_out region (overwritten later by attn_kernel) ---
    u16* xbf   = (u16*)att_out;          // 4,194,304 u16 (8 MB)
    u16* wqbf  = xbf  + 4194304;         // 1,048,576 u16 (2 MB)
    u16* wkbf  = wqbf + 1048576;         //   262,144 u16 (0.5 MB)
    u16* wvbf  = wkbf + 262144;          //   262,144 u16 (0.5 MB)
    float* ct  = (float*)(wvbf + 262144); // 65,536 f32 (256 KB)
    float* st  = ct + 65536;             // 65,536 f32 (256 KB)
    // --- post-attention scratch (K/V and fp32-Y dead by then) ---
    u16* ybf   = (u16*)kws;              // 4,194,304 u16 (8 MB, spans kws+vws)
    u16* wobf  = (u16*)qws;              // 1,048,576 u16 (2 MB, qws front)

    // bf16 pre-conversion (RNE, identical to previous in-loop rounding)
    convert_bf16<<<2048, 256, 0, stream>>>(x,  xbf,  524288);   // X:  4M elems
    convert_bf16<<<512,  256, 0, stream>>>(Wq, wqbf, 131072);   // Wq: 1M
    convert_bf16<<<128,  256, 0, stream>>>(Wk, wkbf, 32768);    // Wk: 256K
    convert_bf16<<<128,  256, 0, stream>>>(Wv, wvbf, 32768);    // Wv: 256K
    rope_table<<<256, 256, 0, stream>>>(ct, st);                // 65K unique (t,ii), double precision

    qkv_gemm<<<dim3(24, 256), 256, 0, stream>>>(xbf, wqbf, wkbf, wvbf, bq, bk, bv, qws, kws, vws);
    rope_apply<<<dim3((B_*HQ_*T_*32 + B_*HKV_*T_*32) / 256), 256, 0, stream>>>(qws, kws, ct, st);
    attn_kernel<<<dim3(T_ / 4, B_ * HQ_), 256, 0, stream>>>(qws, kws, vws, att_out);

    convert_bf16<<<2048, 256, 0, stream>>>(qws, ybf, 524288);   // Y fp32 -> bf16 (into kws+vws)
    convert_bf16<<<512,  256, 0, stream>>>(Wo,  wobf, 131072);  // Wo -> bf16 (into qws front)
    out_gemm<<<dim3(16, 256), 256, 0, stream>>>(ybf, wobf, bo, out);
}

// Round 2
// 1256.366 us; speedup vs baseline: 1.8611x; 1.8611x over previous
//
#include <hip/hip_runtime.h>
#include <hip/hip_bf16.h>
#include <math.h>

typedef unsigned short u16;
typedef unsigned int u32;
typedef short bf16x8 __attribute__((ext_vector_type(8)));
typedef float f32x4 __attribute__((ext_vector_type(4)));

#define B_ 2
#define T_ 2048
#define E_ 1024
#define HQ_ 16
#define HKV_ 4
#define D_ 64
#define G_ 4

__device__ __forceinline__ u16 f2bf(float f) {
    union { float f; unsigned int i; } v; v.f = f;
    unsigned int x = v.i;
    return (u16)((x + 0x7fffu + ((x >> 16) & 1u)) >> 16);
}

__device__ __forceinline__ bf16x8 cvt8(const float* p) {
    float4 a = *(const float4*)p;
    float4 b = *(const float4*)(p + 4);
    bf16x8 r;
    r[0] = (short)f2bf(a.x); r[1] = (short)f2bf(a.y);
    r[2] = (short)f2bf(a.z); r[3] = (short)f2bf(a.w);
    r[4] = (short)f2bf(b.x); r[5] = (short)f2bf(b.y);
    r[6] = (short)f2bf(b.z); r[7] = (short)f2bf(b.w);
    return r;
}

// ---------------- fp32 -> bf16 bulk converter (RNE)
__global__ __launch_bounds__(256) void convert_bf16(const float* __restrict__ src,
                                                    u16* __restrict__ dst, int n8) {
    int i = blockIdx.x * blockDim.x + threadIdx.x;
    if (i >= n8) return;
    bf16x8 r = cvt8(src + (size_t)i * 8);
    *(bf16x8*)(dst + (size_t)i * 8) = r;
}

// ---------------- RoPE cos/sin table: 2048 x 32 unique (t, ii) pairs, double precision
__global__ __launch_bounds__(256) void rope_table(float* __restrict__ ct, float* __restrict__ st) {
    int gid = blockIdx.x * blockDim.x + threadIdx.x;   // 65536
    int t = gid >> 5, ii = gid & 31;
    double theta = pow(10000.0, -(double)ii / 32.0);
    double ang = (double)(t + 1) * theta;
    ct[gid] = (float)cos(ang);
    st[gid] = (float)sin(ang);
}

// ---------------- QKV projection: C(4096x1536) = X(4096x1024) @ [Wq|Wk|Wv] + bias
// Q,K written fp32 (rope needs fp32); V written directly as bf16.
__global__ __launch_bounds__(256) void qkv_gemm(
    const u16* __restrict__ Xb,
    const u16* __restrict__ Wqb, const u16* __restrict__ Wkb, const u16* __restrict__ Wvb,
    const float* __restrict__ bq, const float* __restrict__ bk, const float* __restrict__ bv,
    float* __restrict__ qws, float* __restrict__ kws, u16* __restrict__ vbh)
{
    int lane = threadIdx.x & 63;
    int wave = threadIdx.x >> 6;
    int l16 = lane & 15;
    int quad = lane >> 4;
    int mtile = blockIdx.y;                 // 0..255
    int ntile = blockIdx.x * 4 + wave;      // 0..95
    int m = mtile * 16 + l16;
    int n = ntile * 16 + l16;

    const u16* W; int ldw; const float* bias; int ncol;
    if (n < 1024)      { W = Wqb; ldw = 1024; bias = bq; ncol = n; }
    else if (n < 1280) { W = Wkb; ldw = 256;  bias = bk; ncol = n - 1024; }
    else               { W = Wvb; ldw = 256;  bias = bv; ncol = n - 1280; }

    f32x4 acc = {0.f, 0.f, 0.f, 0.f};
    const u16* arow = Xb + (size_t)m * 1024 + quad * 8;
    for (int kk = 0; kk < 1024; kk += 32) {
        bf16x8 a = *(const bf16x8*)(arow + kk);
        const u16* wp = W + (size_t)(kk + quad * 8) * ldw + ncol;
        bf16x8 b;
        #pragma unroll
        for (int j = 0; j < 8; ++j) b[j] = (short)wp[(size_t)j * ldw];
        acc = __builtin_amdgcn_mfma_f32_16x16x32_bf16(a, b, acc, 0, 0, 0);
    }

    float bs = bias[ncol];
    #pragma unroll
    for (int r = 0; r < 4; ++r) {
        int rowm = mtile * 16 + quad * 4 + r;
        int bb = rowm >> 11, t = rowm & (T_ - 1);
        float h = acc[r] + bs;
        if (n < 1024) {
            int hq = n >> 6, dd = n & 63;
            qws[(((size_t)(bb * HQ_ + hq)) * T_ + t) * D_ + dd] = h;
        } else if (n < 1280) {
            int c2 = n - 1024; int kvh = c2 >> 6, dd = c2 & 63;
            kws[(((size_t)(bb * HKV_ + kvh)) * T_ + t) * D_ + dd] = h;
        } else {
            int c2 = n - 1280; int kvh = c2 >> 6, dd = c2 & 63;
            vbh[(((size_t)(bb * HKV_ + kvh)) * T_ + t) * D_ + dd] = f2bf(h);
        }
    }
}

// ---------------- RoPE apply: Q in place fp32; K -> bf16 (rounded once, reused by all attn blocks)
__global__ void rope_apply(float* __restrict__ qws, const float* __restrict__ kws,
                           u16* __restrict__ kbh,
                           const float* __restrict__ ct, const float* __restrict__ st) {
    const int QP = B_ * HQ_ * T_ * 32;   // 2,097,152
    const int KP = B_ * HKV_ * T_ * 32;  //   524,288
    int gid = blockIdx.x * blockDim.x + threadIdx.x;
    if (gid >= QP + KP) return;
    int ii = gid & 31;
    if (gid < QP) {
        int row = gid >> 5;
        float* base = qws + (size_t)row * 64;
        int t = row & (T_ - 1);
        float c = ct[t * 32 + ii];
        float s = st[t * 32 + ii];
        float x1 = base[ii];
        float x2 = base[ii + 32];
        base[ii]      = x1 * c - x2 * s;
        base[ii + 32] = x2 * c + x1 * s;
    } else {
        int row = (gid - QP) >> 5;
        const float* base = kws + (size_t)row * 64;
        int t = row & (T_ - 1);
        float c = ct[t * 32 + ii];
        float s = st[t * 32 + ii];
        float x1 = base[ii];
        float x2 = base[ii + 32];
        kbh[(size_t)row * 64 + ii]      = f2bf(x1 * c - x2 * s);
        kbh[(size_t)row * 64 + ii + 32] = f2bf(x2 * c + x1 * s);
    }
}

// ---------------- attention: one block per (bh, 16 query rows). MFMA QK^T + PV.
// S in LDS fp32 (stride 2052 -> 2-way-max bank aliasing, free per G4).
// Q: fp32 -> bf16 hi/lo in-kernel (near-fp32 scores). K,V: bf16 single.
// After exp, S is repacked in place as (ph | pl<<16) u32; att_out written from p~=ph+pl (2^-16 rel).
__global__ __launch_bounds__(256) void attn_kernel(
    float* __restrict__ qws, const u16* __restrict__ kbh, const u16* __restrict__ vbh,
    float* __restrict__ att_out)
{
    __shared__ __align__(16) float S[16 * 2052];   // 131,328 B
    __shared__ __align__(16) float qs[16 * 68];    // 4,352 B
    __shared__ float sinv[16];
    int tid = threadIdx.x;
    int lane = tid & 63, wave = tid >> 6;
    int l16 = lane & 15, quad = lane >> 4;
    int i0 = blockIdx.x * 16;
    int bh = blockIdx.y;
    int b = bh >> 4, hq = bh & 15;
    int kvh = hq >> 2, g = hq & 3;
    float* qbase = qws + ((size_t)bh * T_ + i0) * 64;
    const u16* kb = kbh + (size_t)(b * HKV_ + kvh) * T_ * 64;
    const u16* vb = vbh + (size_t)(b * HKV_ + kvh) * T_ * 64;

    // Q tile 16x64 -> LDS
    for (int idx = tid; idx < 1024; idx += 256)
        qs[(idx >> 6) * 68 + (idx & 63)] = qbase[idx];
    __syncthreads();

    // per-lane Q A-frags, hi/lo, for the two 32-wide k-steps
    bf16x8 Qh[2], Ql[2];
    #pragma unroll
    for (int s = 0; s < 2; ++s) {
        const float* qp = qs + l16 * 68 + s * 32 + quad * 8;
        #pragma unroll
        for (int j = 0; j < 8; ++j) {
            float x = qp[j];
            u16 h = f2bf(x);
            float fh = __uint_as_float((u32)h << 16);
            Qh[s][j] = (short)h;
            Ql[s][j] = (short)f2bf(x - fh);
        }
    }

    int ncb = blockIdx.x + 1;            // 16-wide col-blocks to compute (causal)
    // ---- scores: S[16][j] = (Q/8) . K_j   (hi/lo split on Q)
    for (int cb = wave; cb < ncb; cb += 4) {
        const u16* kp = kb + (size_t)(cb * 16 + l16) * 64 + quad * 8;
        bf16x8 b0 = *(const bf16x8*)kp;
        bf16x8 b1 = *(const bf16x8*)(kp + 32);
        f32x4 acc = {0.f, 0.f, 0.f, 0.f};
        acc = __builtin_amdgcn_mfma_f32_16x16x32_bf16(Qh[0], b0, acc, 0, 0, 0);
        acc = __builtin_amdgcn_mfma_f32_16x16x32_bf16(Ql[0], b0, acc, 0, 0, 0);
        acc = __builtin_amdgcn_mfma_f32_16x16x32_bf16(Qh[1], b1, acc, 0, 0, 0);
        acc = __builtin_amdgcn_mfma_f32_16x16x32_bf16(Ql[1], b1, acc, 0, 0, 0);
        #pragma unroll
        for (int r = 0; r < 4; ++r)
            S[(quad * 4 + r) * 2052 + cb * 16 + l16] = acc[r] * 0.125f;
    }
    __syncthreads();

    // ---- softmax: 16 threads per row; exp in fp32; repack P as bf16 hi/lo in place
    int row = tid >> 4, sub = tid & 15;
    int rowlim = i0 + row;
    int njk = (i0 + 47) >> 5;            // 32-wide k-steps for PV
    int njk32 = njk << 5;
    float* Srow = S + row * 2052;
    u32* Prow = (u32*)Srow;
    float m = -1e30f;
    for (int j = sub; j <= rowlim; j += 16) m = fmaxf(m, Srow[j]);
    #pragma unroll
    for (int off = 1; off < 16; off <<= 1) m = fmaxf(m, __shfl_xor(m, off, 64));
    float sum = 0.f;
    for (int j = sub; j < njk32; j += 16) {
        float s = Srow[j];
        float p = (j <= rowlim) ? __expf(s - m) : 0.f;
        sum += p;
        u16 ph = f2bf(p);
        float fh = __uint_as_float((u32)ph << 16);
        u16 pl = f2bf(p - fh);
        Prow[j] = (u32)ph | ((u32)pl << 16);
    }
    #pragma unroll
    for (int off = 1; off < 16; off <<= 1) sum += __shfl_xor(sum, off, 64);
    if (sub == 0) sinv[row] = 1.f / sum;
    __syncthreads();

    // ---- att_weights write (fp32, coalesced float4), zeros beyond causal frontier
    size_t abase = (((size_t)(b * G_ + g) * HKV_ + kvh) * T_ + i0) * T_;
    for (int r = 0; r < 16; ++r) {
        float iv = sinv[r];
        const u32* Pr = (const u32*)(S + r * 2052);
        for (int j4 = tid * 4; j4 < T_; j4 += 1024) {
            float4 o;
            float vals[4];
            #pragma unroll
            for (int e = 0; e < 4; ++e) {
                int j = j4 + e;
                float pt = 0.f;
                if (j < njk32) {
                    u32 u = Pr[j];
                    pt = __uint_as_float(u << 16) + __uint_as_float(u & 0xffff0000u);
                }
                vals[e] = pt * iv;
            }
            o.x = vals[0]; o.y = vals[1]; o.z = vals[2]; o.w = vals[3];
            *(float4*)(att_out + abase + (size_t)r * T_ + j4) = o;
        }
    }

    // ---- P @ V via MFMA (P hi/lo x V bf16); each wave owns 16 of the 64 d-cols
    {
        int dcol = wave * 16 + l16;
        f32x4 acc = {0.f, 0.f, 0.f, 0.f};
        for (int jb = 0; jb < njk; ++jb) {
            const u32* pp = (const u32*)(S + l16 * 2052) + jb * 32 + quad * 8;
            bf16x8 Ah, Al;
            #pragma unroll
            for (int j = 0; j < 8; ++j) {
                u32 u = pp[j];
                Ah[j] = (short)(u & 0xffffu);
                Al[j] = (short)(u >> 16);
            }
            const u16* vp = vb + (size_t)(jb * 32 + quad * 8) * 64 + dcol;
            bf16x8 Vf;
            #pragma unroll
            for (int j = 0; j < 8; ++j) Vf[j] = (short)vp[(size_t)j * 64];
            acc = __builtin_amdgcn_mfma_f32_16x16x32_bf16(Ah, Vf, acc, 0, 0, 0);
            acc = __builtin_amdgcn_mfma_f32_16x16x32_bf16(Al, Vf, acc, 0, 0, 0);
        }
        // y -> bf16, written into the low half of this block's own Q-row footprints
        u16* yw = (u16*)qws;
        #pragma unroll
        for (int r = 0; r < 4; ++r) {
            int rr = quad * 4 + r;
            float y = acc[r] * sinv[rr];
            yw[(size_t)(bh * T_ + i0 + rr) * 128 + dcol] = f2bf(y);
        }
    }
}

// ---------------- output projection: out(4096x1024) = Y @ Wo + bo
// Y is bf16 with row stride 128 u16 (written in-place over Q rows by attn)
__global__ __launch_bounds__(256) void out_gemm(
    const u16* __restrict__ Yb, const u16* __restrict__ Wob, const float* __restrict__ bo,
    float* __restrict__ out)
{
    int lane = threadIdx.x & 63;
    int wave = threadIdx.x >> 6;
    int l16 = lane & 15;
    int quad = lane >> 4;
    int mtile = blockIdx.y;                 // 0..255
    int ntile = blockIdx.x * 4 + wave;      // 0..63
    int m = mtile * 16 + l16;
    int n = ntile * 16 + l16;
    int bb = m >> 11, t = m & (T_ - 1);

    f32x4 acc = {0.f, 0.f, 0.f, 0.f};
    for (int kk = 0; kk < 1024; kk += 32) {
        int ch = kk + quad * 8;            // 8-aligned, never straddles a 64-wide head
        int hq = ch >> 6, d0 = ch & 63;
        const u16* ap = Yb + ((size_t)(bb * HQ_ + hq) * T_ + t) * 128 + d0;
        bf16x8 a = *(const bf16x8*)ap;
        const u16* wp = Wob + (size_t)ch * 1024 + n;
        bf16x8 b;
        #pragma unroll
        for (int j = 0; j < 8; ++j) b[j] = (short)wp[(size_t)j * 1024];
        acc = __builtin_amdgcn_mfma_f32_16x16x32_bf16(a, b, acc, 0, 0, 0);
    }
    float bs = bo[n];
    #pragma unroll
    for (int r = 0; r < 4; ++r) {
        int rowm = mtile * 16 + quad * 4 + r;
        out[(size_t)rowm * 1024 + n] = acc[r] + bs;
    }
}

extern "C" void kernel_launch(void* const* d_in, const int* in_sizes, int n_in,
                              void* d_out, int out_size, void* d_ws, size_t ws_size,
                              hipStream_t stream) {
    const float* x  = (const float*)d_in[0];
    // d_in[1] = mask (int32) — causal triu, applied analytically
    const float* Wq = (const float*)d_in[2];
    const float* bq = (const float*)d_in[3];
    const float* Wk = (const float*)d_in[4];
    const float* bk = (const float*)d_in[5];
    const float* Wv = (const float*)d_in[6];
    const float* bv = (const float*)d_in[7];
    const float* Wo = (const float*)d_in[8];
    const float* bo = (const float*)d_in[9];

    float* out = (float*)d_out;
    // workspace layout (24 MB total):
    float* qws = (float*)d_ws;                  // [0, 4M) floats: Q fp32 (B,HQ,T,D); later y bf16 in-place
    float* kws = qws + 4194304;                 // [4M, 5M): K fp32 pre-rope
    u16*  kbh = (u16*)(kws + 1048576);          // 1M u16 (2 MB): K bf16 post-rope
    u16*  vbh = kbh + 1048576;                  // 1M u16 (2 MB): V bf16
    float* att_out = out + 4194304;             // (B,G,HKV,T,T) fp32 — 537 MB, dead until attn_kernel

    // --- scratch carved from the att_out region (fully consumed before attn_kernel runs) ---
    u16* xbf   = (u16*)att_out;                 // 4M u16 (8 MB)
    u16* wqbf  = xbf  + 4194304;                // 1M u16 (2 MB)
    u16* wkbf  = wqbf + 1048576;                // 256K u16
    u16* wvbf  = wkbf + 262144;                 // 256K u16
    float* ct  = (float*)(wvbf + 262144);       // 65,536 f32
    float* st  = ct + 65536;                    // 65,536 f32
    // --- post-rope scratch (K fp32 dead after rope_apply) ---
    u16* wobf  = (u16*)kws;                     // 1M u16 (2 MB) in the K fp32 region

    convert_bf16<<<2048, 256, 0, stream>>>(x,  xbf,  524288);
    convert_bf16<<<512,  256, 0, stream>>>(Wq, wqbf, 131072);
    convert_bf16<<<128,  256, 0, stream>>>(Wk, wkbf, 32768);
    convert_bf16<<<128,  256, 0, stream>>>(Wv, wvbf, 32768);
    rope_table<<<256, 256, 0, stream>>>(ct, st);

    qkv_gemm<<<dim3(24, 256), 256, 0, stream>>>(xbf, wqbf, wkbf, wvbf, bq, bk, bv, qws, kws, vbh);
    rope_apply<<<dim3((B_*HQ_*T_*32 + B_*HKV_*T_*32) / 256), 256, 0, stream>>>(qws, kws, kbh, ct, st);
    convert_bf16<<<512, 256, 0, stream>>>(Wo, wobf, 131072);   // after rope_apply: K fp32 now dead

    attn_kernel<<<dim3(T_ / 16, B_ * HQ_), 256, 0, stream>>>(qws, kbh, vbh, att_out);
    out_gemm<<<dim3(16, 256), 256, 0, stream>>>((const u16*)qws, wobf, bo, out);
}

// Round 3
// 1144.879 us; speedup vs baseline: 2.0424x; 1.0974x over previous
//
#include <hip/hip_runtime.h>
#include <hip/hip_bf16.h>
#include <math.h>

typedef unsigned short u16;
typedef unsigned int u32;
typedef short bf16x8 __attribute__((ext_vector_type(8)));
typedef float f32x4 __attribute__((ext_vector_type(4)));

#define B_ 2
#define T_ 2048
#define E_ 1024
#define HQ_ 16
#define HKV_ 4
#define D_ 64
#define G_ 4

__device__ __forceinline__ u16 f2bf(float f) {
    union { float f; unsigned int i; } v; v.f = f;
    unsigned int x = v.i;
    return (u16)((x + 0x7fffu + ((x >> 16) & 1u)) >> 16);
}

__device__ __forceinline__ bf16x8 cvt8(const float* p) {
    float4 a = *(const float4*)p;
    float4 b = *(const float4*)(p + 4);
    bf16x8 r;
    r[0] = (short)f2bf(a.x); r[1] = (short)f2bf(a.y);
    r[2] = (short)f2bf(a.z); r[3] = (short)f2bf(a.w);
    r[4] = (short)f2bf(b.x); r[5] = (short)f2bf(b.y);
    r[6] = (short)f2bf(b.z); r[7] = (short)f2bf(b.w);
    return r;
}

// ---------------- fp32 -> bf16 bulk converter (RNE)
__global__ __launch_bounds__(256) void convert_bf16(const float* __restrict__ src,
                                                    u16* __restrict__ dst, int n8) {
    int i = blockIdx.x * blockDim.x + threadIdx.x;
    if (i >= n8) return;
    bf16x8 r = cvt8(src + (size_t)i * 8);
    *(bf16x8*)(dst + (size_t)i * 8) = r;
}

// ---------------- W [K][N] f32  ->  WT [N][K] bf16 (transpose + convert, LDS tiled)
__global__ __launch_bounds__(256) void wt_kernel(const float* __restrict__ W,
                                                 u16* __restrict__ WT, int K, int N) {
    __shared__ float t[32][33];
    int kt = blockIdx.x * 32, nt = blockIdx.y * 32;
    for (int i = threadIdx.x; i < 1024; i += 256) {
        int r = i >> 5, c = i & 31;
        t[r][c] = W[(size_t)(kt + r) * N + nt + c];
    }
    __syncthreads();
    for (int i = threadIdx.x; i < 1024; i += 256) {
        int r = i >> 5, c = i & 31;
        WT[(size_t)(nt + r) * K + kt + c] = f2bf(t[c][r]);
    }
}

// ---------------- V [bk][2048][64] bf16 -> VT [bk][64][2048] bf16
__global__ __launch_bounds__(256) void vt_kernel(const u16* __restrict__ V, u16* __restrict__ VT) {
    __shared__ u16 t[64][65];
    int jt = blockIdx.x * 64;
    int bk = blockIdx.y;
    const u16* src = V + (size_t)bk * T_ * 64;
    u16* dst = VT + (size_t)bk * 64 * T_;
    for (int i = threadIdx.x; i < 4096; i += 256) {
        int r = i >> 6, c = i & 63;
        t[r][c] = src[(size_t)(jt + r) * 64 + c];
    }
    __syncthreads();
    for (int i = threadIdx.x; i < 4096; i += 256) {
        int r = i >> 6, c = i & 63;
        dst[(size_t)r * T_ + jt + c] = t[c][r];
    }
}

// ---------------- RoPE cos/sin table (double precision, 2048x32 unique pairs)
__global__ __launch_bounds__(256) void rope_table(float* __restrict__ ct, float* __restrict__ st) {
    int gid = blockIdx.x * blockDim.x + threadIdx.x;   // 65536
    int t = gid >> 5, ii = gid & 31;
    double theta = pow(10000.0, -(double)ii / 32.0);
    double ang = (double)(t + 1) * theta;
    ct[gid] = (float)cos(ang);
    st[gid] = (float)sin(ang);
}

// ---------------- QKV projection with transposed bf16 weights: contiguous A and B frag loads
__global__ __launch_bounds__(256) void qkv_gemm(
    const u16* __restrict__ Xb,
    const u16* __restrict__ WqT, const u16* __restrict__ WkT, const u16* __restrict__ WvT,
    const float* __restrict__ bq, const float* __restrict__ bk, const float* __restrict__ bv,
    float* __restrict__ qws, float* __restrict__ kws, u16* __restrict__ vbh)
{
    int lane = threadIdx.x & 63;
    int wave = threadIdx.x >> 6;
    int l16 = lane & 15;
    int quad = lane >> 4;
    int mtile = blockIdx.y;                 // 0..255
    int ntile = blockIdx.x * 4 + wave;      // 0..95
    int m = mtile * 16 + l16;
    int n = ntile * 16 + l16;

    const u16* Wt; const float* bias; int ncol;
    if (n < 1024)      { Wt = WqT; bias = bq; ncol = n; }
    else if (n < 1280) { Wt = WkT; bias = bk; ncol = n - 1024; }
    else               { Wt = WvT; bias = bv; ncol = n - 1280; }

    f32x4 acc = {0.f, 0.f, 0.f, 0.f};
    const u16* arow = Xb + (size_t)m * 1024 + quad * 8;
    const u16* brow = Wt + (size_t)ncol * 1024 + quad * 8;
    for (int kk = 0; kk < 1024; kk += 32) {
        bf16x8 a = *(const bf16x8*)(arow + kk);
        bf16x8 b = *(const bf16x8*)(brow + kk);
        acc = __builtin_amdgcn_mfma_f32_16x16x32_bf16(a, b, acc, 0, 0, 0);
    }

    float bs = bias[ncol];
    #pragma unroll
    for (int r = 0; r < 4; ++r) {
        int rowm = mtile * 16 + quad * 4 + r;
        int bb = rowm >> 11, t = rowm & (T_ - 1);
        float h = acc[r] + bs;
        if (n < 1024) {
            int hq = n >> 6, dd = n & 63;
            qws[(((size_t)(bb * HQ_ + hq)) * T_ + t) * D_ + dd] = h;
        } else if (n < 1280) {
            int c2 = n - 1024; int kvh = c2 >> 6, dd = c2 & 63;
            kws[(((size_t)(bb * HKV_ + kvh)) * T_ + t) * D_ + dd] = h;
        } else {
            int c2 = n - 1280; int kvh = c2 >> 6, dd = c2 & 63;
            vbh[(((size_t)(bb * HKV_ + kvh)) * T_ + t) * D_ + dd] = f2bf(h);
        }
    }
}

// ---------------- RoPE apply: Q in place fp32; K -> bf16
__global__ void rope_apply(float* __restrict__ qws, const float* __restrict__ kws,
                           u16* __restrict__ kbh,
                           const float* __restrict__ ct, const float* __restrict__ st) {
    const int QP = B_ * HQ_ * T_ * 32;   // 2,097,152
    const int KP = B_ * HKV_ * T_ * 32;  //   524,288
    int gid = blockIdx.x * blockDim.x + threadIdx.x;
    if (gid >= QP + KP) return;
    int ii = gid & 31;
    if (gid < QP) {
        int row = gid >> 5;
        float* base = qws + (size_t)row * 64;
        int t = row & (T_ - 1);
        float c = ct[t * 32 + ii];
        float s = st[t * 32 + ii];
        float x1 = base[ii];
        float x2 = base[ii + 32];
        base[ii]      = x1 * c - x2 * s;
        base[ii + 32] = x2 * c + x1 * s;
    } else {
        int row = (gid - QP) >> 5;
        const float* base = kws + (size_t)row * 64;
        int t = row & (T_ - 1);
        float c = ct[t * 32 + ii];
        float s = st[t * 32 + ii];
        float x1 = base[ii];
        float x2 = base[ii + 32];
        kbh[(size_t)row * 64 + ii]      = f2bf(x1 * c - x2 * s);
        kbh[(size_t)row * 64 + ii + 32] = f2bf(x2 * c + x1 * s);
    }
}

// ---------------- attention, 3-pass flash-style: no full-row S storage.
// Pass A: row max (recompute scores). Pass B: row sum. Pass C: p = exp(s-m)*inv ->
// per-wave LDS panel -> coalesced att_out write + PV MFMA (V^T contiguous B-frags).
// LDS ~30 KB -> multiple blocks/CU (vs 136 KB before).
__global__ __launch_bounds__(256) void attn_kernel(
    float* __restrict__ qws, const u16* __restrict__ kbh, const u16* __restrict__ vbt,
    float* __restrict__ att_out)
{
    __shared__ __align__(16) float qs[16 * 68];        // 4.25 KB
    __shared__ __align__(16) u32 panel[4][16 * 36];    // 9 KB (stride 36 u32: 16B-aligned rows)
    __shared__ __align__(16) float yred[4][16 * 64];   // 16 KB
    __shared__ float redm[4][16];
    __shared__ float mf[16];
    __shared__ float sinv[16];

    int tid = threadIdx.x;
    int lane = tid & 63, wave = tid >> 6;
    int l16 = lane & 15, quad = lane >> 4;
    int i0 = blockIdx.x * 16;
    int bh = blockIdx.y;
    int b = bh >> 4, hq = bh & 15;
    int kvh = hq >> 2, g = hq & 3;
    float* qbase = qws + ((size_t)bh * T_ + i0) * 64;
    const u16* kb = kbh + (size_t)(b * HKV_ + kvh) * T_ * 64;
    const u16* vb = vbt + (size_t)(b * HKV_ + kvh) * 64 * T_;
    int ncb = blockIdx.x + 1;            // 16-wide col-blocks with any valid element
    int npairs = (ncb + 1) >> 1;         // 32-wide pairs processed in pass C

    // Q tile 16x64 -> LDS
    for (int idx = tid; idx < 1024; idx += 256)
        qs[(idx >> 6) * 68 + (idx & 63)] = qbase[idx];

    // zero-fill att cols beyond the pass-C region (independent of all compute)
    size_t abase = (((size_t)(b * G_ + g) * HKV_ + kvh) * T_ + i0) * T_;
    {
        int z0 = npairs * 32;
        float4 zz; zz.x = 0.f; zz.y = 0.f; zz.z = 0.f; zz.w = 0.f;
        for (int r = 0; r < 16; ++r)
            for (int j4 = z0 + (tid << 2); j4 < T_; j4 += 1024)
                *(float4*)(att_out + abase + (size_t)r * T_ + j4) = zz;
    }
    __syncthreads();

    // per-lane Q A-frags, hi/lo split (near-fp32 scores)
    bf16x8 Qh[2], Ql[2];
    #pragma unroll
    for (int s = 0; s < 2; ++s) {
        const float* qp = qs + l16 * 68 + s * 32 + quad * 8;
        #pragma unroll
        for (int j = 0; j < 8; ++j) {
            float x = qp[j];
            u16 h = f2bf(x);
            float fh = __uint_as_float((u32)h << 16);
            Qh[s][j] = (short)h;
            Ql[s][j] = (short)f2bf(x - fh);
        }
    }

    // ---- pass A: row max
    float mx[4] = {-1e30f, -1e30f, -1e30f, -1e30f};
    for (int cb = wave; cb < ncb; cb += 4) {
        const u16* kp = kb + (size_t)(cb * 16 + l16) * 64 + quad * 8;
        bf16x8 b0 = *(const bf16x8*)kp;
        bf16x8 b1 = *(const bf16x8*)(kp + 32);
        f32x4 acc = {0.f, 0.f, 0.f, 0.f};
        acc = __builtin_amdgcn_mfma_f32_16x16x32_bf16(Qh[0], b0, acc, 0, 0, 0);
        acc = __builtin_amdgcn_mfma_f32_16x16x32_bf16(Ql[0], b0, acc, 0, 0, 0);
        acc = __builtin_amdgcn_mfma_f32_16x16x32_bf16(Qh[1], b1, acc, 0, 0, 0);
        acc = __builtin_amdgcn_mfma_f32_16x16x32_bf16(Ql[1], b1, acc, 0, 0, 0);
        int j = cb * 16 + l16;
        #pragma unroll
        for (int r = 0; r < 4; ++r) {
            float s = acc[r] * 0.125f;
            if (j <= i0 + quad * 4 + r) mx[r] = fmaxf(mx[r], s);
        }
    }
    #pragma unroll
    for (int off = 8; off >= 1; off >>= 1) {
        #pragma unroll
        for (int r = 0; r < 4; ++r) mx[r] = fmaxf(mx[r], __shfl_xor(mx[r], off, 64));
    }
    if (l16 == 0) {
        #pragma unroll
        for (int r = 0; r < 4; ++r) redm[wave][quad * 4 + r] = mx[r];
    }
    __syncthreads();
    if (tid < 16)
        mf[tid] = fmaxf(fmaxf(redm[0][tid], redm[1][tid]),
                        fmaxf(redm[2][tid], redm[3][tid]));
    __syncthreads();

    float mrow[4];
    #pragma unroll
    for (int r = 0; r < 4; ++r) mrow[r] = mf[quad * 4 + r];

    // ---- pass B: row sum
    float sm[4] = {0.f, 0.f, 0.f, 0.f};
    for (int cb = wave; cb < ncb; cb += 4) {
        const u16* kp = kb + (size_t)(cb * 16 + l16) * 64 + quad * 8;
        bf16x8 b0 = *(const bf16x8*)kp;
        bf16x8 b1 = *(const bf16x8*)(kp + 32);
        f32x4 acc = {0.f, 0.f, 0.f, 0.f};
        acc = __builtin_amdgcn_mfma_f32_16x16x32_bf16(Qh[0], b0, acc, 0, 0, 0);
        acc = __builtin_amdgcn_mfma_f32_16x16x32_bf16(Ql[0], b0, acc, 0, 0, 0);
        acc = __builtin_amdgcn_mfma_f32_16x16x32_bf16(Qh[1], b1, acc, 0, 0, 0);
        acc = __builtin_amdgcn_mfma_f32_16x16x32_bf16(Ql[1], b1, acc, 0, 0, 0);
        int j = cb * 16 + l16;
        #pragma unroll
        for (int r = 0; r < 4; ++r) {
            float s = acc[r] * 0.125f;
            float p = (j <= i0 + quad * 4 + r) ? __expf(s - mrow[r]) : 0.f;
            sm[r] += p;
        }
    }
    #pragma unroll
    for (int off = 8; off >= 1; off >>= 1) {
        #pragma unroll
        for (int r = 0; r < 4; ++r) sm[r] += __shfl_xor(sm[r], off, 64);
    }
    if (l16 == 0) {
        #pragma unroll
        for (int r = 0; r < 4; ++r) redm[wave][quad * 4 + r] = sm[r];
    }
    __syncthreads();
    if (tid < 16)
        sinv[tid] = 1.f / (redm[0][tid] + redm[1][tid] + redm[2][tid] + redm[3][tid]);
    __syncthreads();

    float ivrow[4];
    #pragma unroll
    for (int r = 0; r < 4; ++r) ivrow[r] = sinv[quad * 4 + r];

    // ---- pass C: normalized p -> panel -> att write + PV
    u32* pan = &panel[wave][0];
    f32x4 accv[4] = {{0.f,0.f,0.f,0.f},{0.f,0.f,0.f,0.f},{0.f,0.f,0.f,0.f},{0.f,0.f,0.f,0.f}};
    for (int pc = wave; pc < npairs; pc += 4) {
        int j0 = pc * 32;
        #pragma unroll
        for (int h = 0; h < 2; ++h) {
            int cb = (j0 >> 4) + h;
            const u16* kp = kb + (size_t)(cb * 16 + l16) * 64 + quad * 8;
            bf16x8 b0 = *(const bf16x8*)kp;
            bf16x8 b1 = *(const bf16x8*)(kp + 32);
            f32x4 acc = {0.f, 0.f, 0.f, 0.f};
            acc = __builtin_amdgcn_mfma_f32_16x16x32_bf16(Qh[0], b0, acc, 0, 0, 0);
            acc = __builtin_amdgcn_mfma_f32_16x16x32_bf16(Ql[0], b0, acc, 0, 0, 0);
            acc = __builtin_amdgcn_mfma_f32_16x16x32_bf16(Qh[1], b1, acc, 0, 0, 0);
            acc = __builtin_amdgcn_mfma_f32_16x16x32_bf16(Ql[1], b1, acc, 0, 0, 0);
            int j = cb * 16 + l16;
            #pragma unroll
            for (int r = 0; r < 4; ++r) {
                float s = acc[r] * 0.125f;
                float p = (j <= i0 + quad * 4 + r) ? __expf(s - mrow[r]) * ivrow[r] : 0.f;
                u16 ph = f2bf(p);
                float fh = __uint_as_float((u32)ph << 16);
                u16 pl = f2bf(p - fh);
                pan[(quad * 4 + r) * 36 + h * 16 + l16] = (u32)ph | ((u32)pl << 16);
            }
        }
        // att_out write from panel (coalesced float4, 128B row segments)
        {
            int rbase = lane >> 3;
            int c4 = (lane & 7) * 4;
            #pragma unroll
            for (int it = 0; it < 2; ++it) {
                int rr = it * 8 + rbase;
                uint4 u4 = *(uint4*)&pan[rr * 36 + c4];
                float4 o;
                o.x = __uint_as_float(u4.x << 16) + __uint_as_float(u4.x & 0xffff0000u);
                o.y = __uint_as_float(u4.y << 16) + __uint_as_float(u4.y & 0xffff0000u);
                o.z = __uint_as_float(u4.z << 16) + __uint_as_float(u4.z & 0xffff0000u);
                o.w = __uint_as_float(u4.w << 16) + __uint_as_float(u4.w & 0xffff0000u);
                *(float4*)(att_out + abase + (size_t)rr * T_ + j0 + c4) = o;
            }
        }
        // PV: A-frag from panel (lane l16 = q-row, k = quad*8+jj), B-frag from V^T contiguous
        bf16x8 Ah, Al;
        {
            const u32* pp = &pan[l16 * 36 + quad * 8];
            #pragma unroll
            for (int jj = 0; jj < 8; ++jj) {
                u32 u = pp[jj];
                Ah[jj] = (short)(u & 0xffffu);
                Al[jj] = (short)(u >> 16);
            }
        }
        #pragma unroll
        for (int dt = 0; dt < 4; ++dt) {
            const u16* vp = vb + (size_t)(dt * 16 + l16) * T_ + j0 + quad * 8;
            bf16x8 Vf = *(const bf16x8*)vp;
            accv[dt] = __builtin_amdgcn_mfma_f32_16x16x32_bf16(Ah, Vf, accv[dt], 0, 0, 0);
            accv[dt] = __builtin_amdgcn_mfma_f32_16x16x32_bf16(Al, Vf, accv[dt], 0, 0, 0);
        }
    }

    // cross-wave PV reduce
    #pragma unroll
    for (int dt = 0; dt < 4; ++dt) {
        #pragma unroll
        for (int r = 0; r < 4; ++r)
            yred[wave][(quad * 4 + r) * 64 + dt * 16 + l16] = accv[dt][r];
    }
    __syncthreads();
    // combine + write y bf16 in place over this block's Q rows (row stride 128 u16)
    u16* yw = (u16*)qws;
    for (int i = tid; i < 1024; i += 256) {
        int row = i >> 6, d = i & 63;
        float y = yred[0][i] + yred[1][i] + yred[2][i] + yred[3][i];
        yw[((size_t)bh * T_ + i0 + row) * 128 + d] = f2bf(y);
    }
}

// ---------------- output projection with transposed bf16 Wo: contiguous A and B frags
__global__ __launch_bounds__(256) void out_gemm(
    const u16* __restrict__ Yb, const u16* __restrict__ WoT, const float* __restrict__ bo,
    float* __restrict__ out)
{
    int lane = threadIdx.x & 63;
    int wave = threadIdx.x >> 6;
    int l16 = lane & 15;
    int quad = lane >> 4;
    int mtile = blockIdx.y;                 // 0..255
    int ntile = blockIdx.x * 4 + wave;      // 0..63
    int m = mtile * 16 + l16;
    int n = ntile * 16 + l16;
    int bb = m >> 11, t = m & (T_ - 1);

    f32x4 acc = {0.f, 0.f, 0.f, 0.f};
    const u16* brow = WoT + (size_t)n * 1024 + quad * 8;
    for (int kk = 0; kk < 1024; kk += 32) {
        int ch = kk + quad * 8;
        int hq = ch >> 6, d0 = ch & 63;
        const u16* ap = Yb + ((size_t)(bb * HQ_ + hq) * T_ + t) * 128 + d0;
        bf16x8 a = *(const bf16x8*)ap;
        bf16x8 b = *(const bf16x8*)(brow + kk);
        acc = __builtin_amdgcn_mfma_f32_16x16x32_bf16(a, b, acc, 0, 0, 0);
    }
    float bs = bo[n];
    #pragma unroll
    for (int r = 0; r < 4; ++r) {
        int rowm = mtile * 16 + quad * 4 + r;
        out[(size_t)rowm * 1024 + n] = acc[r] + bs;
    }
}

extern "C" void kernel_launch(void* const* d_in, const int* in_sizes, int n_in,
                              void* d_out, int out_size, void* d_ws, size_t ws_size,
                              hipStream_t stream) {
    const float* x  = (const float*)d_in[0];
    // d_in[1] = mask (int32) — causal triu, applied analytically
    const float* Wq = (const float*)d_in[2];
    const float* bq = (const float*)d_in[3];
    const float* Wk = (const float*)d_in[4];
    const float* bk = (const float*)d_in[5];
    const float* Wv = (const float*)d_in[6];
    const float* bv = (const float*)d_in[7];
    const float* Wo = (const float*)d_in[8];
    const float* bo = (const float*)d_in[9];

    float* out = (float*)d_out;
    // workspace (24 MB):
    float* qws = (float*)d_ws;                  // 16 MB: Q fp32 (B,HQ,T,D); later y bf16 in place
    float* kws = qws + 4194304;                 // 4 MB: K fp32 pre-rope; later WoT + V^T bf16
    u16*  kbh = (u16*)(kws + 1048576);          // 2 MB: K bf16 post-rope
    u16*  vbh = kbh + 1048576;                  // 2 MB: V bf16 [j][d]
    float* att_out = out + 4194304;             // 537 MB, dead until attn_kernel

    // scratch carved from att_out region (fully consumed before attn_kernel):
    u16* xbf   = (u16*)att_out;                 // 8 MB
    u16* wqT   = xbf  + 4194304;                // 2 MB   WqT [1024][1024]
    u16* wkT   = wqT  + 1048576;                // 0.5 MB WkT [256][1024]
    u16* wvT   = wkT  + 262144;                 // 0.5 MB WvT [256][1024]
    float* ct  = (float*)(wvT + 262144);        // 256 KB
    float* st  = ct + 65536;                    // 256 KB
    // post-rope scratch in the dead K-fp32 region:
    u16* woT   = (u16*)kws;                     // 2 MB   WoT [1024][1024]
    u16* vbt   = woT + 1048576;                 // 2 MB   V^T [b][kvh][64][2048]

    convert_bf16<<<2048, 256, 0, stream>>>(x, xbf, 524288);
    wt_kernel<<<dim3(32, 32), 256, 0, stream>>>(Wq, wqT, 1024, 1024);
    wt_kernel<<<dim3(32, 8),  256, 0, stream>>>(Wk, wkT, 1024, 256);
    wt_kernel<<<dim3(32, 8),  256, 0, stream>>>(Wv, wvT, 1024, 256);
    rope_table<<<256, 256, 0, stream>>>(ct, st);

    qkv_gemm<<<dim3(24, 256), 256, 0, stream>>>(xbf, wqT, wkT, wvT, bq, bk, bv, qws, kws, vbh);
    rope_apply<<<dim3((B_*HQ_*T_*32 + B_*HKV_*T_*32) / 256), 256, 0, stream>>>(qws, kws, kbh, ct, st);
    wt_kernel<<<dim3(32, 32), 256, 0, stream>>>(Wo, woT, 1024, 1024);   // K fp32 now dead
    vt_kernel<<<dim3(32, 8),  256, 0, stream>>>(vbh, vbt);

    attn_kernel<<<dim3(T_ / 16, B_ * HQ_), 256, 0, stream>>>(qws, kbh, vbt, att_out);
    out_gemm<<<dim3(16, 256), 256, 0, stream>>>((const u16*)qws, woT, bo, out);
}

// Round 6
// 981.820 us; speedup vs baseline: 2.3816x; 1.1661x over previous
//
#include <hip/hip_runtime.h>
#include <hip/hip_bf16.h>
#include <math.h>

typedef unsigned short u16;
typedef unsigned int u32;
typedef short bf16x8 __attribute__((ext_vector_type(8)));
typedef float f32x4 __attribute__((ext_vector_type(4)));

#define B_ 2
#define T_ 2048
#define E_ 1024
#define HQ_ 16
#define HKV_ 4
#define D_ 64
#define G_ 4

__device__ __forceinline__ u16 f2bf(float f) {
    union { float f; unsigned int i; } v; v.f = f;
    unsigned int x = v.i;
    return (u16)((x + 0x7fffu + ((x >> 16) & 1u)) >> 16);
}

__device__ __forceinline__ bf16x8 cvt8(const float* p) {
    float4 a = *(const float4*)p;
    float4 b = *(const float4*)(p + 4);
    bf16x8 r;
    r[0] = (short)f2bf(a.x); r[1] = (short)f2bf(a.y);
    r[2] = (short)f2bf(a.z); r[3] = (short)f2bf(a.w);
    r[4] = (short)f2bf(b.x); r[5] = (short)f2bf(b.y);
    r[6] = (short)f2bf(b.z); r[7] = (short)f2bf(b.w);
    return r;
}

// ---------------- fp32 -> bf16 bulk converter (RNE)
__global__ __launch_bounds__(256) void convert_bf16(const float* __restrict__ src,
                                                    u16* __restrict__ dst, int n8) {
    int i = blockIdx.x * blockDim.x + threadIdx.x;
    if (i >= n8) return;
    bf16x8 r = cvt8(src + (size_t)i * 8);
    *(bf16x8*)(dst + (size_t)i * 8) = r;
}

// ---------------- W [K][N] f32  ->  WT [N][K] bf16 (transpose + convert, LDS tiled)
__global__ __launch_bounds__(256) void wt_kernel(const float* __restrict__ W,
                                                 u16* __restrict__ WT, int K, int N) {
    __shared__ float t[32][33];
    int kt = blockIdx.x * 32, nt = blockIdx.y * 32;
    for (int i = threadIdx.x; i < 1024; i += 256) {
        int r = i >> 5, c = i & 31;
        t[r][c] = W[(size_t)(kt + r) * N + nt + c];
    }
    __syncthreads();
    for (int i = threadIdx.x; i < 1024; i += 256) {
        int r = i >> 5, c = i & 31;
        WT[(size_t)(nt + r) * K + kt + c] = f2bf(t[c][r]);
    }
}

// ---------------- V [bk][2048][64] bf16 -> VT [bk][64][2048] bf16
__global__ __launch_bounds__(256) void vt_kernel(const u16* __restrict__ V, u16* __restrict__ VT) {
    __shared__ u16 t[64][65];
    int jt = blockIdx.x * 64;
    int bk = blockIdx.y;
    const u16* src = V + (size_t)bk * T_ * 64;
    u16* dst = VT + (size_t)bk * 64 * T_;
    for (int i = threadIdx.x; i < 4096; i += 256) {
        int r = i >> 6, c = i & 63;
        t[r][c] = src[(size_t)(jt + r) * 64 + c];
    }
    __syncthreads();
    for (int i = threadIdx.x; i < 4096; i += 256) {
        int r = i >> 6, c = i & 63;
        dst[(size_t)r * T_ + jt + c] = t[c][r];
    }
}

// ---------------- RoPE cos/sin table (double precision, 2048x32 unique pairs)
__global__ __launch_bounds__(256) void rope_table(float* __restrict__ ct, float* __restrict__ st) {
    int gid = blockIdx.x * blockDim.x + threadIdx.x;   // 65536
    int t = gid >> 5, ii = gid & 31;
    double theta = pow(10000.0, -(double)ii / 32.0);
    double ang = (double)(t + 1) * theta;
    ct[gid] = (float)cos(ang);
    st[gid] = (float)sin(ang);
}

// ---------------- QKV projection: each wave computes 16x64 (1 A-frag shared by 4 B-frags)
__global__ __launch_bounds__(256) void qkv_gemm(
    const u16* __restrict__ Xb,
    const u16* __restrict__ WqT, const u16* __restrict__ WkT, const u16* __restrict__ WvT,
    const float* __restrict__ bq, const float* __restrict__ bk, const float* __restrict__ bv,
    float* __restrict__ qws, float* __restrict__ kws, u16* __restrict__ vbh)
{
    int lane = threadIdx.x & 63;
    int wave = threadIdx.x >> 6;
    int l16 = lane & 15;
    int quad = lane >> 4;
    int mtile = blockIdx.y;                 // 0..255
    int nt64 = blockIdx.x * 4 + wave;       // 0..23
    int nbase = nt64 * 64;
    int m = mtile * 16 + l16;

    const u16* Wt; const float* bias; int roff;
    if (nbase < 1024)      { Wt = WqT; bias = bq; roff = 0; }
    else if (nbase < 1280) { Wt = WkT; bias = bk; roff = 1024; }
    else                   { Wt = WvT; bias = bv; roff = 1280; }

    const u16* arow = Xb + (size_t)m * 1024 + quad * 8;
    const u16* br0 = Wt + (size_t)(nbase - roff + 0 * 16 + l16) * 1024 + quad * 8;
    const u16* br1 = Wt + (size_t)(nbase - roff + 1 * 16 + l16) * 1024 + quad * 8;
    const u16* br2 = Wt + (size_t)(nbase - roff + 2 * 16 + l16) * 1024 + quad * 8;
    const u16* br3 = Wt + (size_t)(nbase - roff + 3 * 16 + l16) * 1024 + quad * 8;

    f32x4 acc0 = {0.f,0.f,0.f,0.f}, acc1 = {0.f,0.f,0.f,0.f};
    f32x4 acc2 = {0.f,0.f,0.f,0.f}, acc3 = {0.f,0.f,0.f,0.f};
    for (int kk = 0; kk < 1024; kk += 32) {
        bf16x8 a = *(const bf16x8*)(arow + kk);
        acc0 = __builtin_amdgcn_mfma_f32_16x16x32_bf16(a, *(const bf16x8*)(br0 + kk), acc0, 0, 0, 0);
        acc1 = __builtin_amdgcn_mfma_f32_16x16x32_bf16(a, *(const bf16x8*)(br1 + kk), acc1, 0, 0, 0);
        acc2 = __builtin_amdgcn_mfma_f32_16x16x32_bf16(a, *(const bf16x8*)(br2 + kk), acc2, 0, 0, 0);
        acc3 = __builtin_amdgcn_mfma_f32_16x16x32_bf16(a, *(const bf16x8*)(br3 + kk), acc3, 0, 0, 0);
    }

    f32x4 accs[4] = {acc0, acc1, acc2, acc3};
    #pragma unroll
    for (int t = 0; t < 4; ++t) {
        int ncol = nbase - roff + t * 16 + l16;
        int ng = nbase + t * 16 + l16;
        float bs = bias[ncol];
        #pragma unroll
        for (int r = 0; r < 4; ++r) {
            int rowm = mtile * 16 + quad * 4 + r;
            int bb = rowm >> 11, tt = rowm & (T_ - 1);
            float h = accs[t][r] + bs;
            if (ng < 1024) {
                int hq = ng >> 6, dd = ng & 63;
                qws[(((size_t)(bb * HQ_ + hq)) * T_ + tt) * D_ + dd] = h;
            } else if (ng < 1280) {
                int c2 = ng - 1024; int kvh = c2 >> 6, dd = c2 & 63;
                kws[(((size_t)(bb * HKV_ + kvh)) * T_ + tt) * D_ + dd] = h;
            } else {
                int c2 = ng - 1280; int kvh = c2 >> 6, dd = c2 & 63;
                vbh[(((size_t)(bb * HKV_ + kvh)) * T_ + tt) * D_ + dd] = f2bf(h);
            }
        }
    }
}

// ---------------- RoPE apply: Q in place fp32; K -> bf16
__global__ void rope_apply(float* __restrict__ qws, const float* __restrict__ kws,
                           u16* __restrict__ kbh,
                           const float* __restrict__ ct, const float* __restrict__ st) {
    const int QP = B_ * HQ_ * T_ * 32;   // 2,097,152
    const int KP = B_ * HKV_ * T_ * 32;  //   524,288
    int gid = blockIdx.x * blockDim.x + threadIdx.x;
    if (gid >= QP + KP) return;
    int ii = gid & 31;
    if (gid < QP) {
        int row = gid >> 5;
        float* base = qws + (size_t)row * 64;
        int t = row & (T_ - 1);
        float c = ct[t * 32 + ii];
        float s = st[t * 32 + ii];
        float x1 = base[ii];
        float x2 = base[ii + 32];
        base[ii]      = x1 * c - x2 * s;
        base[ii + 32] = x2 * c + x1 * s;
    } else {
        int row = (gid - QP) >> 5;
        const float* base = kws + (size_t)row * 64;
        int t = row & (T_ - 1);
        float c = ct[t * 32 + ii];
        float s = st[t * 32 + ii];
        float x1 = base[ii];
        float x2 = base[ii + 32];
        kbh[(size_t)row * 64 + ii]      = f2bf(x1 * c - x2 * s);
        kbh[(size_t)row * 64 + ii + 32] = f2bf(x2 * c + x1 * s);
    }
}

// ---------------- attention v3: 2-phase flash.
// Phase AB: online max+sum in one QK^T sweep. Phase C: recompute QK^T, p=exp(s-m)*inv
// -> per-wave f32 LDS panel -> att_out float4 write + PV (waves split over d, no reduce).
// LDS ~14 KB -> 6 blocks/CU. Heavy causal tiles scheduled first (reversed blockIdx.x).
__global__ __launch_bounds__(256, 6) void attn_kernel(
    float* __restrict__ qws, const u16* __restrict__ kbh, const u16* __restrict__ vbt,
    float* __restrict__ att_out)
{
    __shared__ __align__(16) float qs[16 * 68];        // 4.25 KB
    __shared__ __align__(16) float panel[4][16 * 36];  // 9 KB (row stride 144 B, 16B-aligned)
    __shared__ float redm[4][16];
    __shared__ float reds[4][16];
    __shared__ float mf[16];
    __shared__ float sinv[16];

    int tid = threadIdx.x;
    int lane = tid & 63, wave = tid >> 6;
    int l16 = lane & 15, quad = lane >> 4;
    int tile = (T_ / 16 - 1) - blockIdx.x;   // reversed: heavy tiles dispatched first
    int i0 = tile * 16;
    int bh = blockIdx.y;
    int b = bh >> 4, hq = bh & 15;
    int kvh = hq >> 2, g = hq & 3;
    float* qbase = qws + ((size_t)bh * T_ + i0) * 64;
    const u16* kb = kbh + (size_t)(b * HKV_ + kvh) * T_ * 64;
    const u16* vb = vbt + (size_t)(b * HKV_ + kvh) * 64 * T_;
    int ncb = tile + 1;                  // valid 16-wide col-blocks
    int npairs = (ncb + 1) >> 1;         // 32-wide chunks in phase C

    // Q tile 16x64 -> LDS
    for (int idx = tid; idx < 1024; idx += 256)
        qs[(idx >> 6) * 68 + (idx & 63)] = qbase[idx];

    // zero-fill att cols beyond the phase-C region
    size_t abase = (((size_t)(b * G_ + g) * HKV_ + kvh) * T_ + i0) * T_;
    {
        int z0 = npairs * 32;
        float4 zz; zz.x = 0.f; zz.y = 0.f; zz.z = 0.f; zz.w = 0.f;
        for (int r = 0; r < 16; ++r)
            for (int j4 = z0 + (tid << 2); j4 < T_; j4 += 1024)
                *(float4*)(att_out + abase + (size_t)r * T_ + j4) = zz;
    }
    __syncthreads();

    // per-lane Q A-frags, hi/lo split (near-fp32 scores)
    bf16x8 Qh[2], Ql[2];
    #pragma unroll
    for (int s = 0; s < 2; ++s) {
        const float* qp = qs + l16 * 68 + s * 32 + quad * 8;
        #pragma unroll
        for (int j = 0; j < 8; ++j) {
            float x = qp[j];
            u16 h = f2bf(x);
            float fh = __uint_as_float((u32)h << 16);
            Qh[s][j] = (short)h;
            Ql[s][j] = (short)f2bf(x - fh);
        }
    }

    // ---- phase AB: one QK^T sweep, online (max, sum) per row
    float mx[4] = {-1e30f, -1e30f, -1e30f, -1e30f};
    float sm[4] = {0.f, 0.f, 0.f, 0.f};
    for (int cb = wave; cb < ncb; cb += 4) {
        const u16* kp = kb + (size_t)(cb * 16 + l16) * 64 + quad * 8;
        bf16x8 b0 = *(const bf16x8*)kp;
        bf16x8 b1 = *(const bf16x8*)(kp + 32);
        f32x4 acc = {0.f, 0.f, 0.f, 0.f};
        acc = __builtin_amdgcn_mfma_f32_16x16x32_bf16(Qh[0], b0, acc, 0, 0, 0);
        acc = __builtin_amdgcn_mfma_f32_16x16x32_bf16(Ql[0], b0, acc, 0, 0, 0);
        acc = __builtin_amdgcn_mfma_f32_16x16x32_bf16(Qh[1], b1, acc, 0, 0, 0);
        acc = __builtin_amdgcn_mfma_f32_16x16x32_bf16(Ql[1], b1, acc, 0, 0, 0);
        int j = cb * 16 + l16;
        #pragma unroll
        for (int r = 0; r < 4; ++r) {
            if (j <= i0 + quad * 4 + r) {
                float x = acc[r] * 0.125f;
                if (x > mx[r]) { sm[r] = sm[r] * __expf(mx[r] - x) + 1.f; mx[r] = x; }
                else           { sm[r] += __expf(x - mx[r]); }
            }
        }
    }
    // combine across the 16 l16-lanes (xor offsets 1,2,4,8 stay within the quad group)
    #pragma unroll
    for (int off = 1; off < 16; off <<= 1) {
        #pragma unroll
        for (int r = 0; r < 4; ++r) {
            float mo = __shfl_xor(mx[r], off, 64);
            float so = __shfl_xor(sm[r], off, 64);
            float mn = fmaxf(mx[r], mo);
            sm[r] = sm[r] * __expf(mx[r] - mn) + so * __expf(mo - mn);
            mx[r] = mn;
        }
    }
    if (l16 == 0) {
        #pragma unroll
        for (int r = 0; r < 4; ++r) { redm[wave][quad * 4 + r] = mx[r]; reds[wave][quad * 4 + r] = sm[r]; }
    }
    __syncthreads();
    if (tid < 16) {
        float M = redm[0][tid], S = reds[0][tid];
        #pragma unroll
        for (int w = 1; w < 4; ++w) {
            float mo = redm[w][tid], so = reds[w][tid];
            float mn = fmaxf(M, mo);
            S = S * __expf(M - mn) + so * __expf(mo - mn);
            M = mn;
        }
        mf[tid] = M;
        sinv[tid] = 1.f / S;
    }
    __syncthreads();

    float mrow[4], ivrow[4];
    #pragma unroll
    for (int r = 0; r < 4; ++r) { mrow[r] = mf[quad * 4 + r]; ivrow[r] = sinv[quad * 4 + r]; }

    // ---- phase C: super-iterations of 4 chunks; produce (per-wave chunk) then
    //      consume (each wave PVs its own 16 d-cols over all 4 panels)
    f32x4 accv = {0.f, 0.f, 0.f, 0.f};
    int nsuper = (npairs + 3) >> 2;
    for (int sp = 0; sp < nsuper; ++sp) {
        int pc = sp * 4 + wave;
        if (pc < npairs) {
            int j0 = pc * 32;
            float* pan = &panel[wave][0];
            #pragma unroll
            for (int h = 0; h < 2; ++h) {
                int cb = (j0 >> 4) + h;
                const u16* kp = kb + (size_t)(cb * 16 + l16) * 64 + quad * 8;
                bf16x8 b0 = *(const bf16x8*)kp;
                bf16x8 b1 = *(const bf16x8*)(kp + 32);
                f32x4 acc = {0.f, 0.f, 0.f, 0.f};
                acc = __builtin_amdgcn_mfma_f32_16x16x32_bf16(Qh[0], b0, acc, 0, 0, 0);
                acc = __builtin_amdgcn_mfma_f32_16x16x32_bf16(Ql[0], b0, acc, 0, 0, 0);
                acc = __builtin_amdgcn_mfma_f32_16x16x32_bf16(Qh[1], b1, acc, 0, 0, 0);
                acc = __builtin_amdgcn_mfma_f32_16x16x32_bf16(Ql[1], b1, acc, 0, 0, 0);
                int j = cb * 16 + l16;
                #pragma unroll
                for (int r = 0; r < 4; ++r) {
                    float s = acc[r] * 0.125f;
                    float p = (j <= i0 + quad * 4 + r) ? __expf(s - mrow[r]) * ivrow[r] : 0.f;
                    pan[(quad * 4 + r) * 36 + h * 16 + l16] = p;
                }
            }
            // att_out write: 16 rows x 32 cols, float4 per lane-segment
            {
                int rbase = lane >> 3;
                int c4 = (lane & 7) * 4;
                #pragma unroll
                for (int it = 0; it < 2; ++it) {
                    int rr = it * 8 + rbase;
                    float4 o = *(float4*)&pan[rr * 36 + c4];
                    *(float4*)(att_out + abase + (size_t)rr * T_ + j0 + c4) = o;
                }
            }
        }
        __syncthreads();
        int np4 = npairs - sp * 4; if (np4 > 4) np4 = 4;
        #pragma unroll 4
        for (int pw = 0; pw < np4; ++pw) {
            const float* pan = &panel[pw][0];
            const float* pp = pan + l16 * 36 + quad * 8;
            bf16x8 Ah;
            #pragma unroll
            for (int jj = 0; jj < 8; ++jj) Ah[jj] = (short)f2bf(pp[jj]);
            int j0 = (sp * 4 + pw) * 32;
            const u16* vp = vb + (size_t)(wave * 16 + l16) * T_ + j0 + quad * 8;
            bf16x8 Vf = *(const bf16x8*)vp;
            accv = __builtin_amdgcn_mfma_f32_16x16x32_bf16(Ah, Vf, accv, 0, 0, 0);
        }
        __syncthreads();
    }

    // y -> bf16, written in place over this block's Q rows (row stride 128 u16)
    {
        u16* yw = (u16*)qws;
        #pragma unroll
        for (int r = 0; r < 4; ++r) {
            int rr = quad * 4 + r;
            yw[((size_t)bh * T_ + i0 + rr) * 128 + wave * 16 + l16] = f2bf(accv[r]);
        }
    }
}

// ---------------- output projection: each wave computes 16x64 (1 A-frag, 4 B-frags)
__global__ __launch_bounds__(256) void out_gemm(
    const u16* __restrict__ Yb, const u16* __restrict__ WoT, const float* __restrict__ bo,
    float* __restrict__ out)
{
    int lane = threadIdx.x & 63;
    int wave = threadIdx.x >> 6;
    int l16 = lane & 15;
    int quad = lane >> 4;
    int mtile = blockIdx.y;                 // 0..255
    int nt64 = blockIdx.x * 4 + wave;       // 0..15
    int nbase = nt64 * 64;
    int m = mtile * 16 + l16;
    int bb = m >> 11, t = m & (T_ - 1);

    const u16* br0 = WoT + (size_t)(nbase + 0 * 16 + l16) * 1024 + quad * 8;
    const u16* br1 = WoT + (size_t)(nbase + 1 * 16 + l16) * 1024 + quad * 8;
    const u16* br2 = WoT + (size_t)(nbase + 2 * 16 + l16) * 1024 + quad * 8;
    const u16* br3 = WoT + (size_t)(nbase + 3 * 16 + l16) * 1024 + quad * 8;

    f32x4 acc0 = {0.f,0.f,0.f,0.f}, acc1 = {0.f,0.f,0.f,0.f};
    f32x4 acc2 = {0.f,0.f,0.f,0.f}, acc3 = {0.f,0.f,0.f,0.f};
    for (int kk = 0; kk < 1024; kk += 32) {
        int ch = kk + quad * 8;
        int hq = ch >> 6, d0 = ch & 63;
        const u16* ap = Yb + ((size_t)(bb * HQ_ + hq) * T_ + t) * 128 + d0;
        bf16x8 a = *(const bf16x8*)ap;
        acc0 = __builtin_amdgcn_mfma_f32_16x16x32_bf16(a, *(const bf16x8*)(br0 + kk), acc0, 0, 0, 0);
        acc1 = __builtin_amdgcn_mfma_f32_16x16x32_bf16(a, *(const bf16x8*)(br1 + kk), acc1, 0, 0, 0);
        acc2 = __builtin_amdgcn_mfma_f32_16x16x32_bf16(a, *(const bf16x8*)(br2 + kk), acc2, 0, 0, 0);
        acc3 = __builtin_amdgcn_mfma_f32_16x16x32_bf16(a, *(const bf16x8*)(br3 + kk), acc3, 0, 0, 0);
    }
    f32x4 accs[4] = {acc0, acc1, acc2, acc3};
    #pragma unroll
    for (int tb = 0; tb < 4; ++tb) {
        int n = nbase + tb * 16 + l16;
        float bs = bo[n];
        #pragma unroll
        for (int r = 0; r < 4; ++r) {
            int rowm = mtile * 16 + quad * 4 + r;
            out[(size_t)rowm * 1024 + n] = accs[tb][r] + bs;
        }
    }
}

extern "C" void kernel_launch(void* const* d_in, const int* in_sizes, int n_in,
                              void* d_out, int out_size, void* d_ws, size_t ws_size,
                              hipStream_t stream) {
    const float* x  = (const float*)d_in[0];
    // d_in[1] = mask (int32) — causal triu, applied analytically
    const float* Wq = (const float*)d_in[2];
    const float* bq = (const float*)d_in[3];
    const float* Wk = (const float*)d_in[4];
    const float* bk = (const float*)d_in[5];
    const float* Wv = (const float*)d_in[6];
    const float* bv = (const float*)d_in[7];
    const float* Wo = (const float*)d_in[8];
    const float* bo = (const float*)d_in[9];

    float* out = (float*)d_out;
    // workspace (24 MB):
    float* qws = (float*)d_ws;                  // 16 MB: Q fp32 (B,HQ,T,D); later y bf16 in place
    float* kws = qws + 4194304;                 // 4 MB: K fp32 pre-rope; later WoT + V^T bf16
    u16*  kbh = (u16*)(kws + 1048576);          // 2 MB: K bf16 post-rope
    u16*  vbh = kbh + 1048576;                  // 2 MB: V bf16 [j][d]
    float* att_out = out + 4194304;             // 537 MB, dead until attn_kernel

    // scratch carved from att_out region (fully consumed before attn_kernel):
    u16* xbf   = (u16*)att_out;                 // 8 MB
    u16* wqT   = xbf  + 4194304;                // 2 MB   WqT [1024][1024]
    u16* wkT   = wqT  + 1048576;                // 0.5 MB WkT [256][1024]
    u16* wvT   = wkT  + 262144;                 // 0.5 MB WvT [256][1024]
    float* ct  = (float*)(wvT + 262144);        // 256 KB
    float* st  = ct + 65536;                    // 256 KB
    // post-rope scratch in the dead K-fp32 region:
    u16* woT   = (u16*)kws;                     // 2 MB   WoT [1024][1024]
    u16* vbt   = woT + 1048576;                 // 2 MB   V^T [b][kvh][64][2048]

    convert_bf16<<<2048, 256, 0, stream>>>(x, xbf, 524288);
    wt_kernel<<<dim3(32, 32), 256, 0, stream>>>(Wq, wqT, 1024, 1024);
    wt_kernel<<<dim3(32, 8),  256, 0, stream>>>(Wk, wkT, 1024, 256);
    wt_kernel<<<dim3(32, 8),  256, 0, stream>>>(Wv, wvT, 1024, 256);
    rope_table<<<256, 256, 0, stream>>>(ct, st);

    qkv_gemm<<<dim3(6, 256), 256, 0, stream>>>(xbf, wqT, wkT, wvT, bq, bk, bv, qws, kws, vbh);
    rope_apply<<<dim3((B_*HQ_*T_*32 + B_*HKV_*T_*32) / 256), 256, 0, stream>>>(qws, kws, kbh, ct, st);
    wt_kernel<<<dim3(32, 32), 256, 0, stream>>>(Wo, woT, 1024, 1024);   // K fp32 now dead
    vt_kernel<<<dim3(32, 8),  256, 0, stream>>>(vbh, vbt);

    attn_kernel<<<dim3(T_ / 16, B_ * HQ_), 256, 0, stream>>>(qws, kbh, vbt, att_out);
    out_gemm<<<dim3(4, 256), 256, 0, stream>>>((const u16*)qws, woT, bo, out);
}